// Round 6
// baseline (3948.056 us; speedup 1.0000x reference)
//
#include <hip/hip_runtime.h>
#include <hip/hip_bf16.h>

// Problem constants (static: B=4, Q0=1000, D=256, NH=8, HD=32, FF=1024, L=6, NL=4, NP=4)
// Inputs: fp32. Outputs: fp32. (Verified R3/R5: bf16 reads NaN; fp32 out writes pass.)
// MHA MUST keep R3's exact per-query FP ordering: top-k set selection is bit-fragile
// (saturated-sigmoid score ties at the keep boundary flip under 1e-6 perturbations).
#define BB 4
#define DD 256

typedef unsigned long long u64;
typedef long long s64;
typedef unsigned int u32;

__device__ __forceinline__ float sigm(float x) { return 1.0f / (1.0f + expf(-x)); }

// ---------------- copy rows (fp32 -> fp32 out region) ----------------
__global__ void k_store(const float* __restrict__ in, float* __restrict__ out, int n) {
    int i = blockIdx.x * 256 + threadIdx.x;
    if (i < n) out[i] = in[i];
}

// ---------------- LayerNorm (D=256, one row per block of 256 threads) ----------------
__global__ void k_ln(const float* __restrict__ x, const float* __restrict__ w,
                     const float* __restrict__ b, float* __restrict__ ln) {
    int row = blockIdx.x, tid = threadIdx.x;
    float v = x[(size_t)row * DD + tid];
    __shared__ float sred[4];
    float s = v;
#pragma unroll
    for (int o = 32; o > 0; o >>= 1) s += __shfl_down(s, o);
    if ((tid & 63) == 0) sred[tid >> 6] = s;
    __syncthreads();
    float mu = (sred[0] + sred[1] + sred[2] + sred[3]) * (1.0f / 256.0f);
    __syncthreads();
    float d = v - mu;
    float s2 = d * d;
#pragma unroll
    for (int o = 32; o > 0; o >>= 1) s2 += __shfl_down(s2, o);
    if ((tid & 63) == 0) sred[tid >> 6] = s2;
    __syncthreads();
    float var = (sred[0] + sred[1] + sred[2] + sred[3]) * (1.0f / 256.0f);
    float r = rsqrtf(var + 1e-5f);
    ln[(size_t)row * DD + tid] = d * r * w[tid] + b[tid];
}

// ---------------- GEMM: C[M,N] = act((A+Pe)[M,K] @ W[N,K]^T + bias) (+ residual) ----------------
// All fp32. 64x64 tile, BK=16, 256 threads, 4x4 microtile.
template <int ACT, int RES, int PE>
__global__ __launch_bounds__(256) void k_gemm(const float* __restrict__ A, const float* __restrict__ Pe,
                                              const float* __restrict__ W, const float* __restrict__ bias,
                                              const float* __restrict__ Rm, float* __restrict__ C,
                                              int M, int N, int K) {
    __shared__ float As[16][64];
    __shared__ float Ws[16][64];
    int tid = threadIdx.x;
    int tx = tid & 15, ty = tid >> 4;
    int row0 = blockIdx.y * 64, col0 = blockIdx.x * 64;
    int lm = tid >> 2, lk = (tid & 3) * 4;
    float acc[4][4] = {{0.f}};
    for (int k0 = 0; k0 < K; k0 += 16) {
        int ar = row0 + lm;
        if (ar < M) {
            float4 av = *(const float4*)(A + (size_t)ar * K + k0 + lk);
            if (PE == 1) {
                float4 pv = *(const float4*)(Pe + (size_t)ar * K + k0 + lk);
                av.x += pv.x; av.y += pv.y; av.z += pv.z; av.w += pv.w;
            }
            As[lk + 0][lm] = av.x; As[lk + 1][lm] = av.y; As[lk + 2][lm] = av.z; As[lk + 3][lm] = av.w;
        } else {
            As[lk + 0][lm] = 0.f; As[lk + 1][lm] = 0.f; As[lk + 2][lm] = 0.f; As[lk + 3][lm] = 0.f;
        }
        float4 wv = *(const float4*)(W + (size_t)(col0 + lm) * K + k0 + lk);  // N multiple of 64
        Ws[lk + 0][lm] = wv.x; Ws[lk + 1][lm] = wv.y; Ws[lk + 2][lm] = wv.z; Ws[lk + 3][lm] = wv.w;
        __syncthreads();
#pragma unroll
        for (int kk = 0; kk < 16; kk++) {
            float a0 = As[kk][(ty << 2) + 0], a1 = As[kk][(ty << 2) + 1];
            float a2 = As[kk][(ty << 2) + 2], a3 = As[kk][(ty << 2) + 3];
            float w0 = Ws[kk][(tx << 2) + 0], w1 = Ws[kk][(tx << 2) + 1];
            float w2 = Ws[kk][(tx << 2) + 2], w3 = Ws[kk][(tx << 2) + 3];
            acc[0][0] += a0 * w0; acc[0][1] += a0 * w1; acc[0][2] += a0 * w2; acc[0][3] += a0 * w3;
            acc[1][0] += a1 * w0; acc[1][1] += a1 * w1; acc[1][2] += a1 * w2; acc[1][3] += a1 * w3;
            acc[2][0] += a2 * w0; acc[2][1] += a2 * w1; acc[2][2] += a2 * w2; acc[2][3] += a2 * w3;
            acc[3][0] += a3 * w0; acc[3][1] += a3 * w1; acc[3][2] += a3 * w2; acc[3][3] += a3 * w3;
        }
        __syncthreads();
    }
#pragma unroll
    for (int i2 = 0; i2 < 4; i2++) {
        int r = row0 + (ty << 2) + i2;
        if (r >= M) continue;
#pragma unroll
        for (int j2 = 0; j2 < 4; j2++) {
            int cc = col0 + (tx << 2) + j2;
            float v = acc[i2][j2] + bias[cc];
            if (ACT == 1) v = fmaxf(v, 0.f);
            if (RES == 1) v += Rm[(size_t)r * N + cc];
            C[(size_t)r * N + cc] = v;
        }
    }
}

// ---------------- MHA: sequential-key flash attention, HD=32, 2 queries/thread ----------------
// Per-query FP order is IDENTICAL to the R3-passing kernel (keys j=0..Qn-1 sequential,
// same dot order, same acc expressions). ILP from two independent query chains.
// grid ((Qn+127)/128, B*NH), block 64.
__global__ __launch_bounds__(64) void k_mha(const float* __restrict__ Qb, const float* __restrict__ Kb,
                                            const float* __restrict__ Vb, float* __restrict__ Ob, int Qn) {
    int bh = blockIdx.y;
    int b = bh >> 3, h = bh & 7;
    int lane = threadIdx.x;
    int qA = blockIdx.x * 128 + lane;
    int qB = qA + 64;
    __shared__ float Ks[64][36];
    __shared__ float Vs[64][36];
    float qv0[32], qv1[32];
    float acc0[32], acc1[32];
#pragma unroll
    for (int c = 0; c < 32; c++) { acc0[c] = 0.f; acc1[c] = 0.f; }
    float m0 = -INFINITY, l0 = 0.f, m1 = -INFINITY, l1 = 0.f;
    const float scale = 0.17677669529663687f;  // 1/sqrt(32)
    bool act0 = qA < Qn, act1 = qB < Qn;
    if (act0) {
        const float4* qp = (const float4*)(Qb + ((size_t)(b * Qn + qA)) * DD + h * 32);
#pragma unroll
        for (int c4 = 0; c4 < 8; c4++) {
            float4 t = qp[c4];
            qv0[c4 * 4 + 0] = t.x * scale; qv0[c4 * 4 + 1] = t.y * scale;
            qv0[c4 * 4 + 2] = t.z * scale; qv0[c4 * 4 + 3] = t.w * scale;
        }
    } else {
#pragma unroll
        for (int c = 0; c < 32; c++) qv0[c] = 0.f;
    }
    if (act1) {
        const float4* qp = (const float4*)(Qb + ((size_t)(b * Qn + qB)) * DD + h * 32);
#pragma unroll
        for (int c4 = 0; c4 < 8; c4++) {
            float4 t = qp[c4];
            qv1[c4 * 4 + 0] = t.x * scale; qv1[c4 * 4 + 1] = t.y * scale;
            qv1[c4 * 4 + 2] = t.z * scale; qv1[c4 * 4 + 3] = t.w * scale;
        }
    } else {
#pragma unroll
        for (int c = 0; c < 32; c++) qv1[c] = 0.f;
    }
    for (int k0 = 0; k0 < Qn; k0 += 64) {
        int nk = Qn - k0; if (nk > 64) nk = 64;
        if (lane < nk) {
            const float4* kp = (const float4*)(Kb + ((size_t)(b * Qn + k0 + lane)) * DD + h * 32);
            const float4* vp = (const float4*)(Vb + ((size_t)(b * Qn + k0 + lane)) * DD + h * 32);
#pragma unroll
            for (int c4 = 0; c4 < 8; c4++) {
                *(float4*)&Ks[lane][c4 * 4] = kp[c4];
                *(float4*)&Vs[lane][c4 * 4] = vp[c4];
            }
        }
        __syncthreads();
#pragma unroll 4
        for (int j = 0; j < nk; j++) {
            float s0 = 0.f, s1 = 0.f;
#pragma unroll
            for (int c = 0; c < 32; c++) {
                float kv = Ks[j][c];
                s0 += qv0[c] * kv;
                s1 += qv1[c] * kv;
            }
            float mn0 = fmaxf(m0, s0);
            float sc0 = expf(m0 - mn0);
            float p0 = expf(s0 - mn0);
            l0 = l0 * sc0 + p0;
            m0 = mn0;
            float mn1 = fmaxf(m1, s1);
            float sc1 = expf(m1 - mn1);
            float p1 = expf(s1 - mn1);
            l1 = l1 * sc1 + p1;
            m1 = mn1;
#pragma unroll
            for (int c = 0; c < 32; c++) {
                float vv = Vs[j][c];
                acc0[c] = acc0[c] * sc0 + p0 * vv;
                acc1[c] = acc1[c] * sc1 + p1 * vv;
            }
        }
        __syncthreads();
    }
    if (act0) {
        float inv = 1.0f / l0;
        float* op = Ob + ((size_t)(b * Qn + qA)) * DD + h * 32;
#pragma unroll
        for (int c = 0; c < 32; c++) op[c] = acc0[c] * inv;
    }
    if (act1) {
        float inv = 1.0f / l1;
        float* op = Ob + ((size_t)(b * Qn + qB)) * DD + h * 32;
#pragma unroll
        for (int c = 0; c < 32; c++) op[c] = acc1[c] * inv;
    }
}

// ---------------- deformable sampling ----------------
__device__ __forceinline__ float d_samp(const float* fp, int W, int H, int x, int y) {
    if (x < 0 || x > W - 1 || y < 0 || y > H - 1) return 0.f;
    return fp[y * W + x];
}
__device__ __forceinline__ float d_bil(const float* fp, int W, int H, float gx, float gy) {
    float fx = (gx + 1.0f) * 0.5f * (float)(W - 1);
    float fy = (gy + 1.0f) * 0.5f * (float)(H - 1);
    float x0f = floorf(fx), y0f = floorf(fy);
    int x0 = (int)x0f, y0 = (int)y0f;
    float wx = fx - x0f, wy = fy - y0f;
    float v00 = d_samp(fp, W, H, x0, y0);
    float v10 = d_samp(fp, W, H, x0 + 1, y0);
    float v01 = d_samp(fp, W, H, x0, y0 + 1);
    float v11 = d_samp(fp, W, H, x0 + 1, y0 + 1);
    return v00 * (1.f - wx) * (1.f - wy) + v10 * wx * (1.f - wy) + v01 * (1.f - wx) * wy + v11 * wx * wy;
}

__global__ __launch_bounds__(256) void k_deform(const float* __restrict__ offL, const float* __restrict__ awL,
                                                const float* __restrict__ ref,
                                                const float* __restrict__ f0, const float* __restrict__ f1,
                                                const float* __restrict__ f2, const float* __restrict__ f3,
                                                float* __restrict__ caf, float* __restrict__ attn_out,
                                                int Qn) {
    int row = blockIdx.x;  // b*Qn + q
    int b = row / Qn;
    int tid = threadIdx.x;
    __shared__ float attn_s[8][16];
    __shared__ float off_s[8][16][2];
    __shared__ float rxy[2];
    if (tid < 8) {
        int h = tid;
        const float* ap = awL + (size_t)row * 128 + h * 16;
        float mx = -INFINITY;
        float e[16];
#pragma unroll
        for (int j = 0; j < 16; j++) mx = fmaxf(mx, ap[j]);
        float ssum = 0.f;
#pragma unroll
        for (int j = 0; j < 16; j++) { e[j] = expf(ap[j] - mx); ssum += e[j]; }
        float inv = 1.0f / ssum;
        float* ao = attn_out + (size_t)row * 128 + h * 16;
#pragma unroll
        for (int j = 0; j < 16; j++) {
            float p = e[j] * inv;
            attn_s[h][j] = p;
            ao[j] = p;
        }
        const float* op = offL + (size_t)row * 256 + h * 32;
#pragma unroll
        for (int j = 0; j < 16; j++) {
            off_s[h][j][0] = tanhf(op[j * 2 + 0]);
            off_s[h][j][1] = tanhf(op[j * 2 + 1]);
        }
    }
    if (tid == 8) {
        rxy[0] = ref[(size_t)row * 2 + 0] * 2.f - 1.f;
        rxy[1] = ref[(size_t)row * 2 + 1] * 2.f - 1.f;
    }
    __syncthreads();
    int h = tid >> 5, c = tid & 31;
    float agg = 0.f;
#pragma unroll
    for (int l = 0; l < 4; l++) {
        const int H = 128 >> l;
        const float* base = (l == 0 ? f0 : l == 1 ? f1 : l == 2 ? f2 : f3);
        const float* fp = base + (size_t)(b * DD + h * 32 + c) * H * H;
#pragma unroll
        for (int p = 0; p < 4; p++) {
            int j = l * 4 + p;
            agg += attn_s[h][j] * d_bil(fp, H, H, rxy[0] + off_s[h][j][0], rxy[1] + off_s[h][j][1]);
        }
    }
    caf[(size_t)row * DD + h * 32 + c] = agg;
}

// ---------------- small per-row 2-output heads ----------------
__global__ __launch_bounds__(64) void k_refinit(const float* __restrict__ hbuf, const float* __restrict__ w2,
                                                const float* __restrict__ b2, float* __restrict__ ref) {
    int row = blockIdx.x, lane = threadIdx.x;
    const float* hp = hbuf + (size_t)row * DD;
    float s0 = 0.f, s1 = 0.f;
#pragma unroll
    for (int d = 0; d < 4; d++) {
        int dd = lane + d * 64;
        float v = hp[dd];
        s0 += v * w2[dd];
        s1 += v * w2[DD + dd];
    }
#pragma unroll
    for (int o = 32; o > 0; o >>= 1) { s0 += __shfl_down(s0, o); s1 += __shfl_down(s1, o); }
    if (lane == 0) {
        ref[(size_t)row * 2 + 0] = sigm(s0 + b2[0]);
        ref[(size_t)row * 2 + 1] = sigm(s1 + b2[1]);
    }
}

__global__ __launch_bounds__(64) void k_refine(const float* __restrict__ out, const float* __restrict__ rw,
                                               const float* __restrict__ rb, float* __restrict__ ref) {
    int row = blockIdx.x, lane = threadIdx.x;
    const float* op = out + (size_t)row * DD;
    float s0 = 0.f, s1 = 0.f;
#pragma unroll
    for (int d = 0; d < 4; d++) {
        int dd = lane + d * 64;
        float v = op[dd];
        s0 += v * rw[dd];
        s1 += v * rw[DD + dd];
    }
#pragma unroll
    for (int o = 32; o > 0; o >>= 1) { s0 += __shfl_down(s0, o); s1 += __shfl_down(s1, o); }
    if (lane == 0) {
        float r0 = ref[(size_t)row * 2 + 0] + tanhf(s0 + rb[0]) * 0.5f;
        float r1 = ref[(size_t)row * 2 + 1] + tanhf(s1 + rb[1]) * 0.5f;
        ref[(size_t)row * 2 + 0] = fminf(fmaxf(r0, 0.f), 1.f);
        ref[(size_t)row * 2 + 1] = fminf(fmaxf(r1, 0.f), 1.f);
    }
}

// ---------------- per-row score = sigmoid(out.score_w + b) (sequential dot, R3 order) ----------------
__global__ __launch_bounds__(64) void k_score(const float* __restrict__ out, const float* __restrict__ sw,
                                              const float* __restrict__ sb, float* __restrict__ score, int R) {
    int r = blockIdx.x * 64 + threadIdx.x;
    if (r >= R) return;
    const float* op = out + (size_t)r * DD;
    float s = sb[0];
    for (int d = 0; d < DD; d++) s += op[d] * sw[d];
    score[r] = sigm(s);
}

// ---------------- top-k (exact jax.lax.top_k: desc value, asc index on ties) ----------------
__global__ __launch_bounds__(256) void k_topk(const float* __restrict__ score, int* __restrict__ idx,
                                              int Qn, int PAD, int keep) {
    __shared__ u64 keys[1024];
    int b = blockIdx.x, tid = threadIdx.x;
    for (int q = tid; q < PAD; q += 256) {
        u64 key;
        if (q < Qn) {
            u32 u = __float_as_uint(score[b * Qn + q]);
            u = (u & 0x80000000u) ? ~u : (u | 0x80000000u);
            u32 hi = ~u;  // descending score, ascending index on ties
            key = (((u64)hi) << 32) | (u32)q;
        } else {
            key = 0xFFFFFFFFFFFFFFFFULL;
        }
        keys[q] = key;
    }
    __syncthreads();
    for (int k = 2; k <= PAD; k <<= 1) {
        for (int j = k >> 1; j > 0; j >>= 1) {
            for (int i = tid; i < PAD; i += 256) {
                int ij = i ^ j;
                if (ij > i) {
                    bool up = ((i & k) == 0);
                    u64 a = keys[i], c = keys[ij];
                    if ((a > c) == up) { keys[i] = c; keys[ij] = a; }
                }
            }
            __syncthreads();
        }
    }
    for (int t = tid; t < keep; t += 256) idx[b * keep + t] = (int)(keys[t] & 0xFFFFFFFFu);
}

__global__ __launch_bounds__(256) void k_gather(const float* __restrict__ osrc, const float* __restrict__ esrc,
                                                const float* __restrict__ rsrc, const int* __restrict__ idx,
                                                float* __restrict__ oT, float* __restrict__ eT,
                                                float* __restrict__ rT, int Qin, int keep) {
    int j = blockIdx.x;
    int b = j / keep;
    int src = idx[j];
    int tid = threadIdx.x;
    size_t srow = (size_t)(b * Qin + src), drow = (size_t)j;
    oT[drow * DD + tid] = osrc[srow * DD + tid];
    eT[drow * DD + tid] = esrc[srow * DD + tid];
    if (tid < 2) rT[drow * 2 + tid] = rsrc[srow * 2 + tid];
}

__global__ __launch_bounds__(256) void k_copyback(const float* __restrict__ oT, const float* __restrict__ eT,
                                                  const float* __restrict__ rT, float* __restrict__ o,
                                                  float* __restrict__ e, float* __restrict__ r) {
    int row = blockIdx.x, tid = threadIdx.x;
    o[(size_t)row * DD + tid] = oT[(size_t)row * DD + tid];
    e[(size_t)row * DD + tid] = eT[(size_t)row * DD + tid];
    if (tid < 2) r[(size_t)row * 2 + tid] = rT[(size_t)row * 2 + tid];
}

// =======================================================================================
extern "C" void kernel_launch(void* const* d_in, const int* in_sizes, int n_in,
                              void* d_out, int out_size, void* d_ws, size_t ws_size,
                              hipStream_t stream) {
    (void)in_sizes; (void)n_in; (void)out_size; (void)ws_size;
    const float* q_obj = (const float*)d_in[0];
    const float* q_emb = (const float*)d_in[1];
    const float* feat0 = (const float*)d_in[2];
    const float* feat1 = (const float*)d_in[3];
    const float* feat2 = (const float*)d_in[4];
    const float* feat3 = (const float*)d_in[5];
    const float* sa_in_w = (const float*)d_in[6];
    const float* sa_in_b = (const float*)d_in[7];
    const float* sa_out_w = (const float*)d_in[8];
    const float* sa_out_b = (const float*)d_in[9];
    const float* off_w = (const float*)d_in[10];
    const float* off_b = (const float*)d_in[11];
    const float* aw_w = (const float*)d_in[12];
    const float* aw_b = (const float*)d_in[13];
    const float* ca_out_w = (const float*)d_in[14];
    const float* ca_out_b = (const float*)d_in[15];
    const float* ff_w1 = (const float*)d_in[16];
    const float* ff_b1 = (const float*)d_in[17];
    const float* ff_w2 = (const float*)d_in[18];
    const float* ff_b2 = (const float*)d_in[19];
    const float* nsa_w = (const float*)d_in[20];
    const float* nsa_b = (const float*)d_in[21];
    const float* nca_w = (const float*)d_in[22];
    const float* nca_b = (const float*)d_in[23];
    const float* nff_w = (const float*)d_in[24];
    const float* nff_b = (const float*)d_in[25];
    const float* ref_w1 = (const float*)d_in[26];
    const float* ref_b1 = (const float*)d_in[27];
    const float* ref_w2 = (const float*)d_in[28];
    const float* ref_b2 = (const float*)d_in[29];
    const float* score_w = (const float*)d_in[30];
    const float* score_b = (const float*)d_in[31];
    const float* refine_w = (const float*)d_in[32];
    const float* refine_b = (const float*)d_in[33];

    float* outf = (float*)d_out;
    float* ws = (float*)d_ws;
    const int RD = 4000 * 256;  // 1,024,000 floats
    float* f_out = ws;
    float* f_emb = ws + RD;
    float* f_ln  = ws + 2 * RD;
    float* sc0   = ws + 3 * RD;  // FFN hidden spans sc0+sc1 (2*RD)
    float* sc1   = ws + 4 * RD;
    float* sc2   = ws + 5 * RD;
    float* f_ref = ws + 6 * RD;                      // 8000 floats
    float* f_sc  = ws + 6 * RD + 8000;               // 4000 floats (scores)
    int*   i_idx = (int*)(ws + 6 * RD + 12032);      // 2000 ints

    static const int Qs[6] = {1000, 500, 250, 125, 62, 31};
    static const s64 out_ofs[6] = {0, 1024000, 1536000, 1792000, 1920000, 1983488};
    static const s64 attn_ofs[6] = {2015232, 2527232, 2783232, 2911232, 2975232, 3006976};

    hipMemcpyAsync(f_out, q_obj, (size_t)RD * 4, hipMemcpyDeviceToDevice, stream);
    hipMemcpyAsync(f_emb, q_emb, (size_t)RD * 4, hipMemcpyDeviceToDevice, stream);

    // initial reference points
    k_gemm<1, 0, 0><<<dim3(4, 63), 256, 0, stream>>>(f_emb, nullptr, ref_w1, ref_b1, nullptr, f_ln, 4000, 256, 256);
    k_refinit<<<4000, 64, 0, stream>>>(f_ln, ref_w2, ref_b2, f_ref);

    for (int i = 0; i < 6; i++) {
        const int Q = Qs[i];
        const int R = BB * Q;
        const int gy = (R + 63) / 64;
        const float* siw = sa_in_w + (size_t)i * 768 * 256;
        const float* sib = sa_in_b + (size_t)i * 768;

        // ---- self attention ----
        k_ln<<<R, 256, 0, stream>>>(f_out, nsa_w + i * 256, nsa_b + i * 256, f_ln);
        k_gemm<0, 0, 1><<<dim3(4, gy), 256, 0, stream>>>(f_ln, f_emb, siw, sib, nullptr, sc0, R, 256, 256);
        k_gemm<0, 0, 1><<<dim3(4, gy), 256, 0, stream>>>(f_ln, f_emb, siw + 65536, sib + 256, nullptr, sc1, R, 256, 256);
        k_gemm<0, 0, 0><<<dim3(4, gy), 256, 0, stream>>>(f_ln, nullptr, siw + 131072, sib + 512, nullptr, sc2, R, 256, 256);
        k_mha<<<dim3((Q + 127) / 128, 32), 64, 0, stream>>>(sc0, sc1, sc2, f_ln, Q);
        k_gemm<0, 1, 0><<<dim3(4, gy), 256, 0, stream>>>(f_ln, nullptr, sa_out_w + (size_t)i * 65536,
                                                         sa_out_b + i * 256, f_out, f_out, R, 256, 256);

        // ---- deformable cross attention ----
        k_ln<<<R, 256, 0, stream>>>(f_out, nca_w + i * 256, nca_b + i * 256, f_ln);
        k_gemm<0, 0, 1><<<dim3(4, gy), 256, 0, stream>>>(f_ln, f_emb, off_w + (size_t)i * 65536, off_b + i * 256,
                                                         nullptr, sc0, R, 256, 256);
        k_gemm<0, 0, 1><<<dim3(2, gy), 256, 0, stream>>>(f_ln, f_emb, aw_w + (size_t)i * 32768, aw_b + i * 128,
                                                         nullptr, sc1, R, 128, 256);
        k_deform<<<R, 256, 0, stream>>>(sc0, sc1, f_ref, feat0, feat1, feat2, feat3, sc2, outf + attn_ofs[i], Q);
        k_gemm<0, 1, 0><<<dim3(4, gy), 256, 0, stream>>>(sc2, nullptr, ca_out_w + (size_t)i * 65536,
                                                         ca_out_b + i * 256, f_out, f_out, R, 256, 256);

        // ---- FFN (hidden chunked: chunk<=2000 rows fits sc0..sc1) ----
        k_ln<<<R, 256, 0, stream>>>(f_out, nff_w + i * 256, nff_b + i * 256, f_ln);
        for (int r0 = 0; r0 < R; r0 += 2000) {
            int mc = R - r0; if (mc > 2000) mc = 2000;
            int gyc = (mc + 63) / 64;
            k_gemm<1, 0, 0><<<dim3(16, gyc), 256, 0, stream>>>(f_ln + (size_t)r0 * 256, nullptr,
                                                               ff_w1 + (size_t)i * 262144, ff_b1 + i * 1024,
                                                               nullptr, sc0, mc, 1024, 256);
            k_gemm<0, 1, 0><<<dim3(4, gyc), 256, 0, stream>>>(sc0, nullptr, ff_w2 + (size_t)i * 262144,
                                                              ff_b2 + i * 256, f_out + (size_t)r0 * 256,
                                                              f_out + (size_t)r0 * 256, mc, 256, 1024);
        }

        // ---- refine ref points, emit layer output ----
        if (i < 5) k_refine<<<R, 64, 0, stream>>>(f_out, refine_w, refine_b, f_ref);
        k_store<<<R, 256, 0, stream>>>(f_out, outf + out_ofs[i], R * 256);

        // ---- top-k select + gather ----
        if (i < 5) {
            int keep = Qs[i + 1];
            int PAD = 1;
            while (PAD < Q) PAD <<= 1;
            k_score<<<(R + 63) / 64, 64, 0, stream>>>(f_out, score_w, score_b, f_sc, R);
            k_topk<<<4, 256, 0, stream>>>(f_sc, i_idx, Q, PAD, keep);
            k_gather<<<4 * keep, 256, 0, stream>>>(f_out, f_emb, f_ref, i_idx, sc0, sc1, sc2, Q, keep);
            k_copyback<<<4 * keep, 256, 0, stream>>>(sc0, sc1, sc2, f_out, f_emb, f_ref);
        }
    }
}

// Round 7
// 3195.143 us; speedup vs baseline: 1.2356x; 1.2356x over previous
//
#include <hip/hip_runtime.h>
#include <hip/hip_bf16.h>

// Problem constants (static: B=4, Q0=1000, D=256, NH=8, HD=32, FF=1024, L=6, NL=4, NP=4)
// Inputs: fp32. Outputs: fp32. (Verified R3/R5/R6.)
// MHA/top-k NUMERICS CONTRACT (R5 failure, R6 confirm): every per-query reduction chain
// (dot c-order, online-softmax j-order, GEMM k-order) must keep R3's exact sequential FP
// ordering — top-k set selection flips under ~1e-6 perturbations and causes O(1) errors.
#define BB 4
#define DD 256

typedef unsigned long long u64;
typedef long long s64;
typedef unsigned int u32;

__device__ __forceinline__ float sigm(float x) { return 1.0f / (1.0f + expf(-x)); }

// ---------------- copy rows (fp32 -> fp32 out region) ----------------
__global__ void k_store(const float* __restrict__ in, float* __restrict__ out, int n) {
    int i = blockIdx.x * 256 + threadIdx.x;
    if (i < n) out[i] = in[i];
}

// ---------------- LayerNorm (D=256, one row per block of 256 threads) ----------------
__global__ void k_ln(const float* __restrict__ x, const float* __restrict__ w,
                     const float* __restrict__ b, float* __restrict__ ln) {
    int row = blockIdx.x, tid = threadIdx.x;
    float v = x[(size_t)row * DD + tid];
    __shared__ float sred[4];
    float s = v;
#pragma unroll
    for (int o = 32; o > 0; o >>= 1) s += __shfl_down(s, o);
    if ((tid & 63) == 0) sred[tid >> 6] = s;
    __syncthreads();
    float mu = (sred[0] + sred[1] + sred[2] + sred[3]) * (1.0f / 256.0f);
    __syncthreads();
    float d = v - mu;
    float s2 = d * d;
#pragma unroll
    for (int o = 32; o > 0; o >>= 1) s2 += __shfl_down(s2, o);
    if ((tid & 63) == 0) sred[tid >> 6] = s2;
    __syncthreads();
    float var = (sred[0] + sred[1] + sred[2] + sred[3]) * (1.0f / 256.0f);
    float r = rsqrtf(var + 1e-5f);
    ln[(size_t)row * DD + tid] = d * r * w[tid] + b[tid];
}

// ---------------- GEMM: C[M,N] = act((A+Pe)[M,K] @ W[N,K]^T + bias) (+ residual) ----------------
// All fp32. 64x64 tile, BK=16, 256 threads, 4x4 microtile. k ascending (order contract).
template <int ACT, int RES, int PE>
__global__ __launch_bounds__(256) void k_gemm(const float* __restrict__ A, const float* __restrict__ Pe,
                                              const float* __restrict__ W, const float* __restrict__ bias,
                                              const float* __restrict__ Rm, float* __restrict__ C,
                                              int M, int N, int K) {
    __shared__ float As[16][64];
    __shared__ float Ws[16][64];
    int tid = threadIdx.x;
    int tx = tid & 15, ty = tid >> 4;
    int row0 = blockIdx.y * 64, col0 = blockIdx.x * 64;
    int lm = tid >> 2, lk = (tid & 3) * 4;
    float acc[4][4] = {{0.f}};
    for (int k0 = 0; k0 < K; k0 += 16) {
        int ar = row0 + lm;
        if (ar < M) {
            float4 av = *(const float4*)(A + (size_t)ar * K + k0 + lk);
            if (PE == 1) {
                float4 pv = *(const float4*)(Pe + (size_t)ar * K + k0 + lk);
                av.x += pv.x; av.y += pv.y; av.z += pv.z; av.w += pv.w;
            }
            As[lk + 0][lm] = av.x; As[lk + 1][lm] = av.y; As[lk + 2][lm] = av.z; As[lk + 3][lm] = av.w;
        } else {
            As[lk + 0][lm] = 0.f; As[lk + 1][lm] = 0.f; As[lk + 2][lm] = 0.f; As[lk + 3][lm] = 0.f;
        }
        float4 wv = *(const float4*)(W + (size_t)(col0 + lm) * K + k0 + lk);  // N multiple of 64
        Ws[lk + 0][lm] = wv.x; Ws[lk + 1][lm] = wv.y; Ws[lk + 2][lm] = wv.z; Ws[lk + 3][lm] = wv.w;
        __syncthreads();
#pragma unroll
        for (int kk = 0; kk < 16; kk++) {
            float a0 = As[kk][(ty << 2) + 0], a1 = As[kk][(ty << 2) + 1];
            float a2 = As[kk][(ty << 2) + 2], a3 = As[kk][(ty << 2) + 3];
            float w0 = Ws[kk][(tx << 2) + 0], w1 = Ws[kk][(tx << 2) + 1];
            float w2 = Ws[kk][(tx << 2) + 2], w3 = Ws[kk][(tx << 2) + 3];
            acc[0][0] += a0 * w0; acc[0][1] += a0 * w1; acc[0][2] += a0 * w2; acc[0][3] += a0 * w3;
            acc[1][0] += a1 * w0; acc[1][1] += a1 * w1; acc[1][2] += a1 * w2; acc[1][3] += a1 * w3;
            acc[2][0] += a2 * w0; acc[2][1] += a2 * w1; acc[2][2] += a2 * w2; acc[2][3] += a2 * w3;
            acc[3][0] += a3 * w0; acc[3][1] += a3 * w1; acc[3][2] += a3 * w2; acc[3][3] += a3 * w3;
        }
        __syncthreads();
    }
#pragma unroll
    for (int i2 = 0; i2 < 4; i2++) {
        int r = row0 + (ty << 2) + i2;
        if (r >= M) continue;
#pragma unroll
        for (int j2 = 0; j2 < 4; j2++) {
            int cc = col0 + (tx << 2) + j2;
            float v = acc[i2][j2] + bias[cc];
            if (ACT == 1) v = fmaxf(v, 0.f);
            if (RES == 1) v += Rm[(size_t)r * N + cc];
            C[(size_t)r * N + cc] = v;
        }
    }
}

// ---------------- MHA: sequential-key flash attention, HD=32, 1 query/thread ----------------
// R3 structure (64-thr block, grid (ceil(Qn/64), B*NH)) + dot software-pipelining:
// per 8-key chunk the 8 dots are computed as independent chains (each with exact c=0..31
// sequential order -> bit-identical), then the 8 online updates run strictly in j order.
// Single-expf trick: of expf(m-mn)/expf(s-mn) one is expf(0)=1; compute only the other.
__global__ __launch_bounds__(64) void k_mha(const float* __restrict__ Qb, const float* __restrict__ Kb,
                                            const float* __restrict__ Vb, float* __restrict__ Ob, int Qn) {
    int bh = blockIdx.y;
    int b = bh >> 3, h = bh & 7;
    int lane = threadIdx.x;
    int qi = blockIdx.x * 64 + lane;
    __shared__ float Ks[64][36];  // +4 pad: conflict-free (R6: SQ_LDS_BANK_CONFLICT=0)
    __shared__ float Vs[64][36];
    float qv[32];
    float acc[32];
#pragma unroll
    for (int c = 0; c < 32; c++) acc[c] = 0.f;
    float m = -INFINITY, l = 0.f;
    const float scale = 0.17677669529663687f;  // 1/sqrt(32)
    bool active = qi < Qn;
    if (active) {
        const float4* qp = (const float4*)(Qb + ((size_t)(b * Qn + qi)) * DD + h * 32);
#pragma unroll
        for (int c4 = 0; c4 < 8; c4++) {
            float4 t = qp[c4];
            qv[c4 * 4 + 0] = t.x * scale; qv[c4 * 4 + 1] = t.y * scale;
            qv[c4 * 4 + 2] = t.z * scale; qv[c4 * 4 + 3] = t.w * scale;
        }
    } else {
#pragma unroll
        for (int c = 0; c < 32; c++) qv[c] = 0.f;
    }
    for (int k0 = 0; k0 < Qn; k0 += 64) {
        int nk = Qn - k0; if (nk > 64) nk = 64;
        if (lane < nk) {
            const float4* kp = (const float4*)(Kb + ((size_t)(b * Qn + k0 + lane)) * DD + h * 32);
            const float4* vp = (const float4*)(Vb + ((size_t)(b * Qn + k0 + lane)) * DD + h * 32);
#pragma unroll
            for (int c4 = 0; c4 < 8; c4++) {
                *(float4*)&Ks[lane][c4 * 4] = kp[c4];
                *(float4*)&Vs[lane][c4 * 4] = vp[c4];
            }
        }
        __syncthreads();
        int j = 0;
        for (; j + 8 <= nk; j += 8) {
            float s[8];
#pragma unroll
            for (int u = 0; u < 8; u++) s[u] = 0.f;
#pragma unroll
            for (int c = 0; c < 32; c++) {
                float q = qv[c];
#pragma unroll
                for (int u = 0; u < 8; u++) s[u] += q * Ks[j + u][c];  // exact c-order per dot
            }
#pragma unroll
            for (int u = 0; u < 8; u++) {
                float sv = s[u];
                float mn = fmaxf(m, sv);
                float e = expf(fminf(m - sv, sv - m));  // == the non-trivial expf of R3
                bool gt = sv > m;
                float sc = gt ? e : 1.0f;
                float p = gt ? 1.0f : e;
                l = l * sc + p;
                m = mn;
#pragma unroll
                for (int c = 0; c < 32; c++) acc[c] = acc[c] * sc + p * Vs[j + u][c];
            }
        }
        for (; j < nk; j++) {
            float sv = 0.f;
#pragma unroll
            for (int c = 0; c < 32; c++) sv += qv[c] * Ks[j][c];
            float mn = fmaxf(m, sv);
            float e = expf(fminf(m - sv, sv - m));
            bool gt = sv > m;
            float sc = gt ? e : 1.0f;
            float p = gt ? 1.0f : e;
            l = l * sc + p;
            m = mn;
#pragma unroll
            for (int c = 0; c < 32; c++) acc[c] = acc[c] * sc + p * Vs[j][c];
        }
        __syncthreads();
    }
    if (active) {
        float inv = 1.0f / l;
        float* op = Ob + ((size_t)(b * Qn + qi)) * DD + h * 32;
#pragma unroll
        for (int c = 0; c < 32; c++) op[c] = acc[c] * inv;
    }
}

// ---------------- deformable sampling ----------------
__device__ __forceinline__ float d_samp(const float* fp, int W, int H, int x, int y) {
    if (x < 0 || x > W - 1 || y < 0 || y > H - 1) return 0.f;
    return fp[y * W + x];
}
__device__ __forceinline__ float d_bil(const float* fp, int W, int H, float gx, float gy) {
    float fx = (gx + 1.0f) * 0.5f * (float)(W - 1);
    float fy = (gy + 1.0f) * 0.5f * (float)(H - 1);
    float x0f = floorf(fx), y0f = floorf(fy);
    int x0 = (int)x0f, y0 = (int)y0f;
    float wx = fx - x0f, wy = fy - y0f;
    float v00 = d_samp(fp, W, H, x0, y0);
    float v10 = d_samp(fp, W, H, x0 + 1, y0);
    float v01 = d_samp(fp, W, H, x0, y0 + 1);
    float v11 = d_samp(fp, W, H, x0 + 1, y0 + 1);
    return v00 * (1.f - wx) * (1.f - wy) + v10 * wx * (1.f - wy) + v01 * (1.f - wx) * wy + v11 * wx * wy;
}

__global__ __launch_bounds__(256) void k_deform(const float* __restrict__ offL, const float* __restrict__ awL,
                                                const float* __restrict__ ref,
                                                const float* __restrict__ f0, const float* __restrict__ f1,
                                                const float* __restrict__ f2, const float* __restrict__ f3,
                                                float* __restrict__ caf, float* __restrict__ attn_out,
                                                int Qn) {
    int row = blockIdx.x;  // b*Qn + q
    int b = row / Qn;
    int tid = threadIdx.x;
    __shared__ float attn_s[8][16];
    __shared__ float off_s[8][16][2];
    __shared__ float rxy[2];
    if (tid < 8) {
        int h = tid;
        const float* ap = awL + (size_t)row * 128 + h * 16;
        float mx = -INFINITY;
        float e[16];
#pragma unroll
        for (int j = 0; j < 16; j++) mx = fmaxf(mx, ap[j]);
        float ssum = 0.f;
#pragma unroll
        for (int j = 0; j < 16; j++) { e[j] = expf(ap[j] - mx); ssum += e[j]; }
        float inv = 1.0f / ssum;
        float* ao = attn_out + (size_t)row * 128 + h * 16;
#pragma unroll
        for (int j = 0; j < 16; j++) {
            float p = e[j] * inv;
            attn_s[h][j] = p;
            ao[j] = p;
        }
        const float* op = offL + (size_t)row * 256 + h * 32;
#pragma unroll
        for (int j = 0; j < 16; j++) {
            off_s[h][j][0] = tanhf(op[j * 2 + 0]);
            off_s[h][j][1] = tanhf(op[j * 2 + 1]);
        }
    }
    if (tid == 8) {
        rxy[0] = ref[(size_t)row * 2 + 0] * 2.f - 1.f;
        rxy[1] = ref[(size_t)row * 2 + 1] * 2.f - 1.f;
    }
    __syncthreads();
    int h = tid >> 5, c = tid & 31;
    float agg = 0.f;
#pragma unroll
    for (int l = 0; l < 4; l++) {
        const int H = 128 >> l;
        const float* base = (l == 0 ? f0 : l == 1 ? f1 : l == 2 ? f2 : f3);
        const float* fp = base + (size_t)(b * DD + h * 32 + c) * H * H;
#pragma unroll
        for (int p = 0; p < 4; p++) {
            int j = l * 4 + p;
            agg += attn_s[h][j] * d_bil(fp, H, H, rxy[0] + off_s[h][j][0], rxy[1] + off_s[h][j][1]);
        }
    }
    caf[(size_t)row * DD + h * 32 + c] = agg;
}

// ---------------- small per-row 2-output heads ----------------
__global__ __launch_bounds__(64) void k_refinit(const float* __restrict__ hbuf, const float* __restrict__ w2,
                                                const float* __restrict__ b2, float* __restrict__ ref) {
    int row = blockIdx.x, lane = threadIdx.x;
    const float* hp = hbuf + (size_t)row * DD;
    float s0 = 0.f, s1 = 0.f;
#pragma unroll
    for (int d = 0; d < 4; d++) {
        int dd = lane + d * 64;
        float v = hp[dd];
        s0 += v * w2[dd];
        s1 += v * w2[DD + dd];
    }
#pragma unroll
    for (int o = 32; o > 0; o >>= 1) { s0 += __shfl_down(s0, o); s1 += __shfl_down(s1, o); }
    if (lane == 0) {
        ref[(size_t)row * 2 + 0] = sigm(s0 + b2[0]);
        ref[(size_t)row * 2 + 1] = sigm(s1 + b2[1]);
    }
}

__global__ __launch_bounds__(64) void k_refine(const float* __restrict__ out, const float* __restrict__ rw,
                                               const float* __restrict__ rb, float* __restrict__ ref) {
    int row = blockIdx.x, lane = threadIdx.x;
    const float* op = out + (size_t)row * DD;
    float s0 = 0.f, s1 = 0.f;
#pragma unroll
    for (int d = 0; d < 4; d++) {
        int dd = lane + d * 64;
        float v = op[dd];
        s0 += v * rw[dd];
        s1 += v * rw[DD + dd];
    }
#pragma unroll
    for (int o = 32; o > 0; o >>= 1) { s0 += __shfl_down(s0, o); s1 += __shfl_down(s1, o); }
    if (lane == 0) {
        float r0 = ref[(size_t)row * 2 + 0] + tanhf(s0 + rb[0]) * 0.5f;
        float r1 = ref[(size_t)row * 2 + 1] + tanhf(s1 + rb[1]) * 0.5f;
        ref[(size_t)row * 2 + 0] = fminf(fmaxf(r0, 0.f), 1.f);
        ref[(size_t)row * 2 + 1] = fminf(fmaxf(r1, 0.f), 1.f);
    }
}

// ---------------- per-row score = sigmoid(out.score_w + b) (sequential dot, R3 order) ----------------
__global__ __launch_bounds__(64) void k_score(const float* __restrict__ out, const float* __restrict__ sw,
                                              const float* __restrict__ sb, float* __restrict__ score, int R) {
    int r = blockIdx.x * 64 + threadIdx.x;
    if (r >= R) return;
    const float* op = out + (size_t)r * DD;
    float s = sb[0];
    for (int d = 0; d < DD; d++) s += op[d] * sw[d];
    score[r] = sigm(s);
}

// ---------------- top-k (exact jax.lax.top_k: desc value, asc index on ties) ----------------
__global__ __launch_bounds__(256) void k_topk(const float* __restrict__ score, int* __restrict__ idx,
                                              int Qn, int PAD, int keep) {
    __shared__ u64 keys[1024];
    int b = blockIdx.x, tid = threadIdx.x;
    for (int q = tid; q < PAD; q += 256) {
        u64 key;
        if (q < Qn) {
            u32 u = __float_as_uint(score[b * Qn + q]);
            u = (u & 0x80000000u) ? ~u : (u | 0x80000000u);
            u32 hi = ~u;  // descending score, ascending index on ties
            key = (((u64)hi) << 32) | (u32)q;
        } else {
            key = 0xFFFFFFFFFFFFFFFFULL;
        }
        keys[q] = key;
    }
    __syncthreads();
    for (int k = 2; k <= PAD; k <<= 1) {
        for (int j = k >> 1; j > 0; j >>= 1) {
            for (int i = tid; i < PAD; i += 256) {
                int ij = i ^ j;
                if (ij > i) {
                    bool up = ((i & k) == 0);
                    u64 a = keys[i], c = keys[ij];
                    if ((a > c) == up) { keys[i] = c; keys[ij] = a; }
                }
            }
            __syncthreads();
        }
    }
    for (int t = tid; t < keep; t += 256) idx[b * keep + t] = (int)(keys[t] & 0xFFFFFFFFu);
}

__global__ __launch_bounds__(256) void k_gather(const float* __restrict__ osrc, const float* __restrict__ esrc,
                                                const float* __restrict__ rsrc, const int* __restrict__ idx,
                                                float* __restrict__ oT, float* __restrict__ eT,
                                                float* __restrict__ rT, int Qin, int keep) {
    int j = blockIdx.x;
    int b = j / keep;
    int src = idx[j];
    int tid = threadIdx.x;
    size_t srow = (size_t)(b * Qin + src), drow = (size_t)j;
    oT[drow * DD + tid] = osrc[srow * DD + tid];
    eT[drow * DD + tid] = esrc[srow * DD + tid];
    if (tid < 2) rT[drow * 2 + tid] = rsrc[srow * 2 + tid];
}

__global__ __launch_bounds__(256) void k_copyback(const float* __restrict__ oT, const float* __restrict__ eT,
                                                  const float* __restrict__ rT, float* __restrict__ o,
                                                  float* __restrict__ e, float* __restrict__ r) {
    int row = blockIdx.x, tid = threadIdx.x;
    o[(size_t)row * DD + tid] = oT[(size_t)row * DD + tid];
    e[(size_t)row * DD + tid] = eT[(size_t)row * DD + tid];
    if (tid < 2) r[(size_t)row * 2 + tid] = rT[(size_t)row * 2 + tid];
}

// =======================================================================================
extern "C" void kernel_launch(void* const* d_in, const int* in_sizes, int n_in,
                              void* d_out, int out_size, void* d_ws, size_t ws_size,
                              hipStream_t stream) {
    (void)in_sizes; (void)n_in; (void)out_size; (void)ws_size;
    const float* q_obj = (const float*)d_in[0];
    const float* q_emb = (const float*)d_in[1];
    const float* feat0 = (const float*)d_in[2];
    const float* feat1 = (const float*)d_in[3];
    const float* feat2 = (const float*)d_in[4];
    const float* feat3 = (const float*)d_in[5];
    const float* sa_in_w = (const float*)d_in[6];
    const float* sa_in_b = (const float*)d_in[7];
    const float* sa_out_w = (const float*)d_in[8];
    const float* sa_out_b = (const float*)d_in[9];
    const float* off_w = (const float*)d_in[10];
    const float* off_b = (const float*)d_in[11];
    const float* aw_w = (const float*)d_in[12];
    const float* aw_b = (const float*)d_in[13];
    const float* ca_out_w = (const float*)d_in[14];
    const float* ca_out_b = (const float*)d_in[15];
    const float* ff_w1 = (const float*)d_in[16];
    const float* ff_b1 = (const float*)d_in[17];
    const float* ff_w2 = (const float*)d_in[18];
    const float* ff_b2 = (const float*)d_in[19];
    const float* nsa_w = (const float*)d_in[20];
    const float* nsa_b = (const float*)d_in[21];
    const float* nca_w = (const float*)d_in[22];
    const float* nca_b = (const float*)d_in[23];
    const float* nff_w = (const float*)d_in[24];
    const float* nff_b = (const float*)d_in[25];
    const float* ref_w1 = (const float*)d_in[26];
    const float* ref_b1 = (const float*)d_in[27];
    const float* ref_w2 = (const float*)d_in[28];
    const float* ref_b2 = (const float*)d_in[29];
    const float* score_w = (const float*)d_in[30];
    const float* score_b = (const float*)d_in[31];
    const float* refine_w = (const float*)d_in[32];
    const float* refine_b = (const float*)d_in[33];

    float* outf = (float*)d_out;
    float* ws = (float*)d_ws;
    const int RD = 4000 * 256;  // 1,024,000 floats
    float* f_out = ws;
    float* f_emb = ws + RD;
    float* f_ln  = ws + 2 * RD;
    float* sc0   = ws + 3 * RD;  // FFN hidden spans sc0+sc1 (2*RD)
    float* sc1   = ws + 4 * RD;
    float* sc2   = ws + 5 * RD;
    float* f_ref = ws + 6 * RD;                      // 8000 floats
    float* f_sc  = ws + 6 * RD + 8000;               // 4000 floats (scores)
    int*   i_idx = (int*)(ws + 6 * RD + 12032);      // 2000 ints

    static const int Qs[6] = {1000, 500, 250, 125, 62, 31};
    static const s64 out_ofs[6] = {0, 1024000, 1536000, 1792000, 1920000, 1983488};
    static const s64 attn_ofs[6] = {2015232, 2527232, 2783232, 2911232, 2975232, 3006976};

    hipMemcpyAsync(f_out, q_obj, (size_t)RD * 4, hipMemcpyDeviceToDevice, stream);
    hipMemcpyAsync(f_emb, q_emb, (size_t)RD * 4, hipMemcpyDeviceToDevice, stream);

    // initial reference points
    k_gemm<1, 0, 0><<<dim3(4, 63), 256, 0, stream>>>(f_emb, nullptr, ref_w1, ref_b1, nullptr, f_ln, 4000, 256, 256);
    k_refinit<<<4000, 64, 0, stream>>>(f_ln, ref_w2, ref_b2, f_ref);

    for (int i = 0; i < 6; i++) {
        const int Q = Qs[i];
        const int R = BB * Q;
        const int gy = (R + 63) / 64;
        const float* siw = sa_in_w + (size_t)i * 768 * 256;
        const float* sib = sa_in_b + (size_t)i * 768;

        // ---- self attention ----
        k_ln<<<R, 256, 0, stream>>>(f_out, nsa_w + i * 256, nsa_b + i * 256, f_ln);
        k_gemm<0, 0, 1><<<dim3(4, gy), 256, 0, stream>>>(f_ln, f_emb, siw, sib, nullptr, sc0, R, 256, 256);
        k_gemm<0, 0, 1><<<dim3(4, gy), 256, 0, stream>>>(f_ln, f_emb, siw + 65536, sib + 256, nullptr, sc1, R, 256, 256);
        k_gemm<0, 0, 0><<<dim3(4, gy), 256, 0, stream>>>(f_ln, nullptr, siw + 131072, sib + 512, nullptr, sc2, R, 256, 256);
        k_mha<<<dim3((Q + 63) / 64, 32), 64, 0, stream>>>(sc0, sc1, sc2, f_ln, Q);
        k_gemm<0, 1, 0><<<dim3(4, gy), 256, 0, stream>>>(f_ln, nullptr, sa_out_w + (size_t)i * 65536,
                                                         sa_out_b + i * 256, f_out, f_out, R, 256, 256);

        // ---- deformable cross attention ----
        k_ln<<<R, 256, 0, stream>>>(f_out, nca_w + i * 256, nca_b + i * 256, f_ln);
        k_gemm<0, 0, 1><<<dim3(4, gy), 256, 0, stream>>>(f_ln, f_emb, off_w + (size_t)i * 65536, off_b + i * 256,
                                                         nullptr, sc0, R, 256, 256);
        k_gemm<0, 0, 1><<<dim3(2, gy), 256, 0, stream>>>(f_ln, f_emb, aw_w + (size_t)i * 32768, aw_b + i * 128,
                                                         nullptr, sc1, R, 128, 256);
        k_deform<<<R, 256, 0, stream>>>(sc0, sc1, f_ref, feat0, feat1, feat2, feat3, sc2, outf + attn_ofs[i], Q);
        k_gemm<0, 1, 0><<<dim3(4, gy), 256, 0, stream>>>(sc2, nullptr, ca_out_w + (size_t)i * 65536,
                                                         ca_out_b + i * 256, f_out, f_out, R, 256, 256);

        // ---- FFN (hidden chunked: chunk<=2000 rows fits sc0..sc1) ----
        k_ln<<<R, 256, 0, stream>>>(f_out, nff_w + i * 256, nff_b + i * 256, f_ln);
        for (int r0 = 0; r0 < R; r0 += 2000) {
            int mc = R - r0; if (mc > 2000) mc = 2000;
            int gyc = (mc + 63) / 64;
            k_gemm<1, 0, 0><<<dim3(16, gyc), 256, 0, stream>>>(f_ln + (size_t)r0 * 256, nullptr,
                                                               ff_w1 + (size_t)i * 262144, ff_b1 + i * 1024,
                                                               nullptr, sc0, mc, 1024, 256);
            k_gemm<0, 1, 0><<<dim3(4, gyc), 256, 0, stream>>>(sc0, nullptr, ff_w2 + (size_t)i * 262144,
                                                              ff_b2 + i * 256, f_out + (size_t)r0 * 256,
                                                              f_out + (size_t)r0 * 256, mc, 256, 1024);
        }

        // ---- refine ref points, emit layer output ----
        if (i < 5) k_refine<<<R, 64, 0, stream>>>(f_out, refine_w, refine_b, f_ref);
        k_store<<<R, 256, 0, stream>>>(f_out, outf + out_ofs[i], R * 256);

        // ---- top-k select + gather ----
        if (i < 5) {
            int keep = Qs[i + 1];
            int PAD = 1;
            while (PAD < Q) PAD <<= 1;
            k_score<<<(R + 63) / 64, 64, 0, stream>>>(f_out, score_w, score_b, f_sc, R);
            k_topk<<<4, 256, 0, stream>>>(f_sc, i_idx, Q, PAD, keep);
            k_gather<<<4 * keep, 256, 0, stream>>>(f_out, f_emb, f_ref, i_idx, sc0, sc1, sc2, Q, keep);
            k_copyback<<<4 * keep, 256, 0, stream>>>(sc0, sc1, sc2, f_out, f_emb, f_ref);
        }
    }
}